// Round 1
// baseline (213.928 us; speedup 1.0000x reference)
//
#include <hip/hip_runtime.h>

#define B_ 2048
#define S_ 256
#define V_ 30522
#define D_ 768
#define C_ 100

// ---------------------------------------------------------------------------
// Kernel 1: embedding gather + masked mean pool.
// One block per sample. 192 threads, each owns one float4 slice of D=768.
// mask/ids loads are wave-uniform (broadcast); row loads are coalesced 16B.
// ---------------------------------------------------------------------------
__global__ __launch_bounds__(192) void pool_kernel(
    const int* __restrict__ ids, const int* __restrict__ mask,
    const float* __restrict__ table, float* __restrict__ bow) {
  const int b = blockIdx.x;
  const int t = threadIdx.x;  // 0..191
  float4 acc = make_float4(0.f, 0.f, 0.f, 0.f);
  int cnt = 0;
  const int base = b * S_;
#pragma unroll 4
  for (int s = 0; s < S_; ++s) {
    const int m = mask[base + s];
    cnt += m;
    if (m) {  // wave-uniform branch
      const int id = ids[base + s];
      const float4 v =
          reinterpret_cast<const float4*>(table + (size_t)id * D_)[t];
      acc.x += v.x; acc.y += v.y; acc.z += v.z; acc.w += v.w;
    }
  }
  const float inv = 1.0f / (float)cnt;
  float4 o;
  o.x = acc.x * inv; o.y = acc.y * inv; o.z = acc.z * inv; o.w = acc.w * inv;
  reinterpret_cast<float4*>(bow + (size_t)b * D_)[t] = o;
}

// ---------------------------------------------------------------------------
// Kernel 2: H = relu(bow @ W1 + b1)   [2048x768] = [2048x768]@[768x768]
// f32 register-tiled GEMM: BM=BN=64, BK=16, 256 threads, 4x4 acc per thread.
// ---------------------------------------------------------------------------
#define BM 64
#define BN 64
#define BK 16

__global__ __launch_bounds__(256) void gemm1_kernel(
    const float* __restrict__ A,    // bow [2048][768]
    const float* __restrict__ Bw,   // W1  [768][768]
    const float* __restrict__ bias, // b1  [768]
    float* __restrict__ H) {        // out [2048][768]
  __shared__ float As[BK][BM];  // A tile stored transposed (k-major)
  __shared__ float Bs[BK][BN];
  const int tid = threadIdx.x;
  const int tx = tid & 15;      // output col group
  const int ty = tid >> 4;      // output row group
  const int bm = blockIdx.x * BM;
  const int bn = blockIdx.y * BN;

  const int arow = tid >> 2;         // 0..63
  const int ak4  = (tid & 3) * 4;    // 0,4,8,12
  const int brow = tid >> 4;         // 0..15
  const int bc4  = (tid & 15) * 4;   // 0..60

  float acc[4][4] = {};

  for (int k0 = 0; k0 < D_; k0 += BK) {
    const float4 av = *reinterpret_cast<const float4*>(
        &A[(size_t)(bm + arow) * D_ + k0 + ak4]);
    const float4 bv = *reinterpret_cast<const float4*>(
        &Bw[(size_t)(k0 + brow) * D_ + bn + bc4]);
    __syncthreads();  // previous iteration done reading LDS
    As[ak4 + 0][arow] = av.x;
    As[ak4 + 1][arow] = av.y;
    As[ak4 + 2][arow] = av.z;
    As[ak4 + 3][arow] = av.w;
    *reinterpret_cast<float4*>(&Bs[brow][bc4]) = bv;
    __syncthreads();
#pragma unroll
    for (int k = 0; k < BK; ++k) {
      const float4 a4 = *reinterpret_cast<const float4*>(&As[k][ty * 4]);
      const float4 b4 = *reinterpret_cast<const float4*>(&Bs[k][tx * 4]);
      const float ar[4] = {a4.x, a4.y, a4.z, a4.w};
      const float br[4] = {b4.x, b4.y, b4.z, b4.w};
#pragma unroll
      for (int i = 0; i < 4; ++i)
#pragma unroll
        for (int j = 0; j < 4; ++j)
          acc[i][j] = fmaf(ar[i], br[j], acc[i][j]);
    }
  }

#pragma unroll
  for (int i = 0; i < 4; ++i) {
    const int row = bm + ty * 4 + i;
    const int col = bn + tx * 4;
    float4 o;
    o.x = acc[i][0] + bias[col + 0];
    o.y = acc[i][1] + bias[col + 1];
    o.z = acc[i][2] + bias[col + 2];
    o.w = acc[i][3] + bias[col + 3];
    o.x = o.x > 0.f ? o.x : 0.f;
    o.y = o.y > 0.f ? o.y : 0.f;
    o.z = o.z > 0.f ? o.z : 0.f;
    o.w = o.w > 0.f ? o.w : 0.f;
    *reinterpret_cast<float4*>(&H[(size_t)row * D_ + col]) = o;
  }
}

// ---------------------------------------------------------------------------
// Kernel 3: scores = H @ W2 + b2   [2048x100] = [2048x768]@[768x100]
// 8 rows per block staged in LDS; thread j (<100) computes col j for all 8
// rows, reusing each W2 element 8x. Output written twice (tuple return).
// ---------------------------------------------------------------------------
#define ROWS 8

__global__ __launch_bounds__(128) void gemm2_kernel(
    const float* __restrict__ H,   // [2048][768]
    const float* __restrict__ W2,  // [768][100]
    const float* __restrict__ b2,  // [100]
    float* __restrict__ out) {     // [2048][100] x2
  __shared__ float hs[ROWS][D_];
  const int m0 = blockIdx.x * ROWS;
  const int t = threadIdx.x;

  // stage 8*768 floats = 1536 float4 with 128 threads (12 each), coalesced
  const float4* src = reinterpret_cast<const float4*>(H + (size_t)m0 * D_);
  float4* dst = reinterpret_cast<float4*>(&hs[0][0]);
#pragma unroll
  for (int i = 0; i < 12; ++i) dst[t + i * 128] = src[t + i * 128];
  __syncthreads();

  if (t < C_) {
    float acc[ROWS] = {};
    for (int k = 0; k < D_; ++k) {
      const float w = W2[(size_t)k * C_ + t];  // coalesced over t
#pragma unroll
      for (int r = 0; r < ROWS; ++r)
        acc[r] = fmaf(hs[r][k], w, acc[r]);  // LDS broadcast
    }
    const float bb = b2[t];
#pragma unroll
    for (int r = 0; r < ROWS; ++r) {
      const float v = acc[r] + bb;
      out[(size_t)(m0 + r) * C_ + t] = v;
      out[(size_t)(m0 + r) * C_ + t + (size_t)B_ * C_] = v;
    }
  }
}

// ---------------------------------------------------------------------------
extern "C" void kernel_launch(void* const* d_in, const int* in_sizes, int n_in,
                              void* d_out, int out_size, void* d_ws,
                              size_t ws_size, hipStream_t stream) {
  const int*   ids   = (const int*)d_in[0];
  const int*   mask  = (const int*)d_in[1];
  const float* table = (const float*)d_in[2];
  const float* W1    = (const float*)d_in[3];
  const float* b1    = (const float*)d_in[4];
  const float* W2    = (const float*)d_in[5];
  const float* b2    = (const float*)d_in[6];
  float* out = (float*)d_out;

  float* bow = (float*)d_ws;                 // [2048][768]
  float* h   = bow + (size_t)B_ * D_;        // [2048][768]

  pool_kernel<<<B_, 192, 0, stream>>>(ids, mask, table, bow);

  dim3 g1(B_ / BM, D_ / BN);
  gemm1_kernel<<<g1, 256, 0, stream>>>(bow, W1, b1, h);

  gemm2_kernel<<<B_ / ROWS, 128, 0, stream>>>(h, W2, b2, out);
}

// Round 2
// 206.443 us; speedup vs baseline: 1.0363x; 1.0363x over previous
//
#include <hip/hip_runtime.h>

#define B_ 2048
#define S_ 256
#define V_ 30522
#define D_ 768
#define C_ 100

// ---------------------------------------------------------------------------
// Kernel 1: embedding gather + masked mean pool.
// One block per sample, 192 threads (3 waves), thread t owns float4 slice t.
// Phase 1: wave 0 compacts valid token ids into LDS (ballot+popc prefix).
// Phase 2: all threads gather rows 8-at-a-time -> 8 outstanding 16B loads
//          per lane (latency hiding), accumulate, scale by 1/cnt.
// ---------------------------------------------------------------------------
__global__ __launch_bounds__(192) void pool_kernel(
    const int* __restrict__ ids, const int* __restrict__ mask,
    const float* __restrict__ table, float* __restrict__ bow) {
  __shared__ int vids[S_];
  __shared__ int s_cnt;
  const int b = blockIdx.x;
  const int t = threadIdx.x;  // 0..191
  const int base = b * S_;

  if (t < 64) {
    int total = 0;
#pragma unroll
    for (int r = 0; r < S_ / 64; ++r) {
      const int s = r * 64 + t;
      const int m = mask[base + s];
      const unsigned long long bal = __ballot(m != 0);
      const int pre = __popcll(bal & ((1ull << t) - 1ull));
      if (m) vids[total + pre] = ids[base + s];
      total += __popcll(bal);
    }
    if (t == 0) s_cnt = total;
  }
  __syncthreads();

  const int cnt = s_cnt;
  float4 acc = make_float4(0.f, 0.f, 0.f, 0.f);

  int i = 0;
  for (; i + 8 <= cnt; i += 8) {
    const float4* p[8];
#pragma unroll
    for (int j = 0; j < 8; ++j)
      p[j] = reinterpret_cast<const float4*>(table + (size_t)vids[i + j] * D_) + t;
    float4 v[8];
#pragma unroll
    for (int j = 0; j < 8; ++j) v[j] = *p[j];  // 8 loads in flight
#pragma unroll
    for (int j = 0; j < 8; ++j) {
      acc.x += v[j].x; acc.y += v[j].y; acc.z += v[j].z; acc.w += v[j].w;
    }
  }
  for (; i < cnt; ++i) {
    const float4 v =
        reinterpret_cast<const float4*>(table + (size_t)vids[i] * D_)[t];
    acc.x += v.x; acc.y += v.y; acc.z += v.z; acc.w += v.w;
  }

  const float inv = 1.0f / (float)cnt;
  float4 o;
  o.x = acc.x * inv; o.y = acc.y * inv; o.z = acc.z * inv; o.w = acc.w * inv;
  reinterpret_cast<float4*>(bow + (size_t)b * D_)[t] = o;
}

// ---------------------------------------------------------------------------
// Kernel 2: H = relu(bow @ W1 + b1)   [2048x768] = [2048x768]@[768x768]
// f32 register-tiled GEMM: BM=BN=64, BK=16, 256 threads, 4x4 acc per thread.
// ---------------------------------------------------------------------------
#define BM 64
#define BN 64
#define BK 16

__global__ __launch_bounds__(256) void gemm1_kernel(
    const float* __restrict__ A,    // bow [2048][768]
    const float* __restrict__ Bw,   // W1  [768][768]
    const float* __restrict__ bias, // b1  [768]
    float* __restrict__ H) {        // out [2048][768]
  __shared__ float As[BK][BM];  // A tile stored transposed (k-major)
  __shared__ float Bs[BK][BN];
  const int tid = threadIdx.x;
  const int tx = tid & 15;      // output col group
  const int ty = tid >> 4;      // output row group
  const int bm = blockIdx.x * BM;
  const int bn = blockIdx.y * BN;

  const int arow = tid >> 2;         // 0..63
  const int ak4  = (tid & 3) * 4;    // 0,4,8,12
  const int brow = tid >> 4;         // 0..15
  const int bc4  = (tid & 15) * 4;   // 0..60

  float acc[4][4] = {};

  for (int k0 = 0; k0 < D_; k0 += BK) {
    const float4 av = *reinterpret_cast<const float4*>(
        &A[(size_t)(bm + arow) * D_ + k0 + ak4]);
    const float4 bv = *reinterpret_cast<const float4*>(
        &Bw[(size_t)(k0 + brow) * D_ + bn + bc4]);
    __syncthreads();  // previous iteration done reading LDS
    As[ak4 + 0][arow] = av.x;
    As[ak4 + 1][arow] = av.y;
    As[ak4 + 2][arow] = av.z;
    As[ak4 + 3][arow] = av.w;
    *reinterpret_cast<float4*>(&Bs[brow][bc4]) = bv;
    __syncthreads();
#pragma unroll
    for (int k = 0; k < BK; ++k) {
      const float4 a4 = *reinterpret_cast<const float4*>(&As[k][ty * 4]);
      const float4 b4 = *reinterpret_cast<const float4*>(&Bs[k][tx * 4]);
      const float ar[4] = {a4.x, a4.y, a4.z, a4.w};
      const float br[4] = {b4.x, b4.y, b4.z, b4.w};
#pragma unroll
      for (int i = 0; i < 4; ++i)
#pragma unroll
        for (int j = 0; j < 4; ++j)
          acc[i][j] = fmaf(ar[i], br[j], acc[i][j]);
    }
  }

#pragma unroll
  for (int i = 0; i < 4; ++i) {
    const int row = bm + ty * 4 + i;
    const int col = bn + tx * 4;
    float4 o;
    o.x = acc[i][0] + bias[col + 0];
    o.y = acc[i][1] + bias[col + 1];
    o.z = acc[i][2] + bias[col + 2];
    o.w = acc[i][3] + bias[col + 3];
    o.x = o.x > 0.f ? o.x : 0.f;
    o.y = o.y > 0.f ? o.y : 0.f;
    o.z = o.z > 0.f ? o.z : 0.f;
    o.w = o.w > 0.f ? o.w : 0.f;
    *reinterpret_cast<float4*>(&H[(size_t)row * D_ + col]) = o;
  }
}

// ---------------------------------------------------------------------------
// Kernel 3: scores = H @ W2 + b2   [2048x100] = [2048x768]@[768x100]
// 8 rows per block staged in LDS; thread j (<100) computes col j for all 8
// rows, reusing each W2 element 8x. Output written twice (tuple return).
// ---------------------------------------------------------------------------
#define ROWS 8

__global__ __launch_bounds__(128) void gemm2_kernel(
    const float* __restrict__ H,   // [2048][768]
    const float* __restrict__ W2,  // [768][100]
    const float* __restrict__ b2,  // [100]
    float* __restrict__ out) {     // [2048][100] x2
  __shared__ float hs[ROWS][D_];
  const int m0 = blockIdx.x * ROWS;
  const int t = threadIdx.x;

  // stage 8*768 floats = 1536 float4 with 128 threads (12 each), coalesced
  const float4* src = reinterpret_cast<const float4*>(H + (size_t)m0 * D_);
  float4* dst = reinterpret_cast<float4*>(&hs[0][0]);
#pragma unroll
  for (int i = 0; i < 12; ++i) dst[t + i * 128] = src[t + i * 128];
  __syncthreads();

  if (t < C_) {
    float acc[ROWS] = {};
    for (int k = 0; k < D_; ++k) {
      const float w = W2[(size_t)k * C_ + t];  // coalesced over t
#pragma unroll
      for (int r = 0; r < ROWS; ++r)
        acc[r] = fmaf(hs[r][k], w, acc[r]);  // LDS broadcast
    }
    const float bb = b2[t];
#pragma unroll
    for (int r = 0; r < ROWS; ++r) {
      const float v = acc[r] + bb;
      out[(size_t)(m0 + r) * C_ + t] = v;
      out[(size_t)(m0 + r) * C_ + t + (size_t)B_ * C_] = v;
    }
  }
}

// ---------------------------------------------------------------------------
extern "C" void kernel_launch(void* const* d_in, const int* in_sizes, int n_in,
                              void* d_out, int out_size, void* d_ws,
                              size_t ws_size, hipStream_t stream) {
  const int*   ids   = (const int*)d_in[0];
  const int*   mask  = (const int*)d_in[1];
  const float* table = (const float*)d_in[2];
  const float* W1    = (const float*)d_in[3];
  const float* b1    = (const float*)d_in[4];
  const float* W2    = (const float*)d_in[5];
  const float* b2    = (const float*)d_in[6];
  float* out = (float*)d_out;

  float* bow = (float*)d_ws;                 // [2048][768]
  float* h   = bow + (size_t)B_ * D_;        // [2048][768]

  pool_kernel<<<B_, 192, 0, stream>>>(ids, mask, table, bow);

  dim3 g1(B_ / BM, D_ / BN);
  gemm1_kernel<<<g1, 256, 0, stream>>>(bow, W1, b1, h);

  gemm2_kernel<<<B_ / ROWS, 128, 0, stream>>>(h, W2, b2, out);
}

// Round 3
// 147.141 us; speedup vs baseline: 1.4539x; 1.4030x over previous
//
#include <hip/hip_runtime.h>

#define B_ 2048
#define S_ 256
#define V_ 30522
#define D_ 768
#define C_ 100

// ---- bf16 helpers (RNE convert; inputs are finite, no NaN handling) -------
__device__ __forceinline__ unsigned short f2bf(float x) {
  unsigned u = __builtin_bit_cast(unsigned, x);
  u = (u + 0x7fffu + ((u >> 16) & 1u)) >> 16;
  return (unsigned short)u;
}
__device__ __forceinline__ float bf2f(unsigned short h) {
  return __builtin_bit_cast(float, ((unsigned)h) << 16);
}

// ---------------------------------------------------------------------------
// Convert embedding table f32 -> bf16 (grid-stride, float4 in / ushort4 out)
// ---------------------------------------------------------------------------
__global__ __launch_bounds__(256) void conv_table(
    const float* __restrict__ src, unsigned short* __restrict__ dst, int n4) {
  int idx = blockIdx.x * blockDim.x + threadIdx.x;
  int stride = gridDim.x * blockDim.x;
  for (int i = idx; i < n4; i += stride) {
    float4 v = reinterpret_cast<const float4*>(src)[i];
    ushort4 o;
    o.x = f2bf(v.x); o.y = f2bf(v.y); o.z = f2bf(v.z); o.w = f2bf(v.w);
    reinterpret_cast<ushort4*>(dst)[i] = o;
  }
}

// ---------------------------------------------------------------------------
// Transpose + convert W1 [768][768] f32 -> W1T [n][k] bf16
// ---------------------------------------------------------------------------
__global__ __launch_bounds__(256) void conv_w1t(
    const float* __restrict__ w1, unsigned short* __restrict__ w1t) {
  __shared__ float tile[32][33];
  const int k0 = blockIdx.x * 32, n0 = blockIdx.y * 32;
  const int tx = threadIdx.x & 31, ty = threadIdx.x >> 5;  // ty 0..7
#pragma unroll
  for (int i = 0; i < 4; ++i)
    tile[ty + i * 8][tx] = w1[(size_t)(k0 + ty + i * 8) * D_ + n0 + tx];
  __syncthreads();
#pragma unroll
  for (int i = 0; i < 4; ++i) {
    const int n = ty + i * 8;
    w1t[(size_t)(n0 + n) * D_ + k0 + tx] = f2bf(tile[tx][n]);
  }
}

// ---------------------------------------------------------------------------
// Pool (bf16 table): ballot-compact valid ids, then gather 16-deep.
// 192 threads; thread t owns 4 bf16 (8B) of D=768. Output bow in bf16.
// ---------------------------------------------------------------------------
__global__ __launch_bounds__(192) void pool_bf16(
    const int* __restrict__ ids, const int* __restrict__ mask,
    const unsigned short* __restrict__ tb, unsigned short* __restrict__ bowb) {
  __shared__ int vids[S_];
  __shared__ int s_cnt;
  const int b = blockIdx.x;
  const int t = threadIdx.x;
  const int base = b * S_;

  if (t < 64) {
    int total = 0;
#pragma unroll
    for (int r = 0; r < S_ / 64; ++r) {
      const int s = r * 64 + t;
      const int m = mask[base + s];
      const unsigned long long bal = __ballot(m != 0);
      const int pre = __popcll(bal & ((1ull << t) - 1ull));
      if (m) vids[total + pre] = ids[base + s];
      total += __popcll(bal);
    }
    if (t == 0) s_cnt = total;
  }
  __syncthreads();

  const int cnt = s_cnt;
  float a0 = 0.f, a1 = 0.f, a2 = 0.f, a3 = 0.f;

  int i = 0;
  for (; i + 16 <= cnt; i += 16) {
    ushort4 v[16];
#pragma unroll
    for (int j = 0; j < 16; ++j)
      v[j] = *(reinterpret_cast<const ushort4*>(tb + (size_t)vids[i + j] * D_) + t);
#pragma unroll
    for (int j = 0; j < 16; ++j) {
      a0 += bf2f(v[j].x); a1 += bf2f(v[j].y);
      a2 += bf2f(v[j].z); a3 += bf2f(v[j].w);
    }
  }
  for (; i < cnt; ++i) {
    const ushort4 v =
        *(reinterpret_cast<const ushort4*>(tb + (size_t)vids[i] * D_) + t);
    a0 += bf2f(v.x); a1 += bf2f(v.y); a2 += bf2f(v.z); a3 += bf2f(v.w);
  }

  const float inv = 1.0f / (float)cnt;
  ushort4 o;
  o.x = f2bf(a0 * inv); o.y = f2bf(a1 * inv);
  o.z = f2bf(a2 * inv); o.w = f2bf(a3 * inv);
  reinterpret_cast<ushort4*>(bowb + (size_t)b * D_)[t] = o;
}

// ---------------------------------------------------------------------------
// Pool fallback (f32 table, if ws too small for bf16 table). bf16 output.
// ---------------------------------------------------------------------------
__global__ __launch_bounds__(192) void pool_f32(
    const int* __restrict__ ids, const int* __restrict__ mask,
    const float* __restrict__ table, unsigned short* __restrict__ bowb) {
  __shared__ int vids[S_];
  __shared__ int s_cnt;
  const int b = blockIdx.x;
  const int t = threadIdx.x;
  const int base = b * S_;

  if (t < 64) {
    int total = 0;
#pragma unroll
    for (int r = 0; r < S_ / 64; ++r) {
      const int s = r * 64 + t;
      const int m = mask[base + s];
      const unsigned long long bal = __ballot(m != 0);
      const int pre = __popcll(bal & ((1ull << t) - 1ull));
      if (m) vids[total + pre] = ids[base + s];
      total += __popcll(bal);
    }
    if (t == 0) s_cnt = total;
  }
  __syncthreads();

  const int cnt = s_cnt;
  float4 acc = make_float4(0.f, 0.f, 0.f, 0.f);
  int i = 0;
  for (; i + 8 <= cnt; i += 8) {
    float4 v[8];
#pragma unroll
    for (int j = 0; j < 8; ++j)
      v[j] = reinterpret_cast<const float4*>(table + (size_t)vids[i + j] * D_)[t];
#pragma unroll
    for (int j = 0; j < 8; ++j) {
      acc.x += v[j].x; acc.y += v[j].y; acc.z += v[j].z; acc.w += v[j].w;
    }
  }
  for (; i < cnt; ++i) {
    const float4 v =
        reinterpret_cast<const float4*>(table + (size_t)vids[i] * D_)[t];
    acc.x += v.x; acc.y += v.y; acc.z += v.z; acc.w += v.w;
  }
  const float inv = 1.0f / (float)cnt;
  ushort4 o;
  o.x = f2bf(acc.x * inv); o.y = f2bf(acc.y * inv);
  o.z = f2bf(acc.z * inv); o.w = f2bf(acc.w * inv);
  reinterpret_cast<ushort4*>(bowb + (size_t)b * D_)[t] = o;
}

// ---------------------------------------------------------------------------
// GEMM1 (MFMA bf16): H = relu(bow @ W1 + b1)
// A = bowb [2048][768] bf16 (k-contig), BT = w1t [768][768] bf16 (k-contig).
// Block 256 thr (4 waves), tile BM=32 x BN=64, BK=32; wave w owns cols
// w*16..+15; 2 m-frags (acc0/acc1). Grid 64x12 = 768 blocks (3/CU).
// ---------------------------------------------------------------------------
typedef __attribute__((ext_vector_type(8))) short bf16x8;
typedef __attribute__((ext_vector_type(4))) float f32x4;

#define G1_BM 32
#define G1_BN 64
#define G1_LDK 40  // 32 + 8 pad (ushorts) -> 80B row stride, 16B aligned

__global__ __launch_bounds__(256) void gemm1_mfma(
    const unsigned short* __restrict__ Ab, const unsigned short* __restrict__ Bt,
    const float* __restrict__ bias, float* __restrict__ H) {
  __shared__ unsigned short As[G1_BM][G1_LDK];
  __shared__ unsigned short Bs[G1_BN][G1_LDK];
  const int tid = threadIdx.x;
  const int bm = blockIdx.x * G1_BM;
  const int bn = blockIdx.y * G1_BN;
  const int w = tid >> 6;
  const int l = tid & 63;
  const int r = l & 15;
  const int g = l >> 4;

  f32x4 acc0 = {0.f, 0.f, 0.f, 0.f};
  f32x4 acc1 = {0.f, 0.f, 0.f, 0.f};

  const int srow = tid >> 2;        // 0..63
  const int sc8 = (tid & 3) * 8;    // 0,8,16,24 (bf16 elems)

  for (int k0 = 0; k0 < D_; k0 += 32) {
    __syncthreads();
    if (tid < 128) {
      const int ar = tid >> 2;      // 0..31
      *reinterpret_cast<int4*>(&As[ar][sc8]) =
          *reinterpret_cast<const int4*>(&Ab[(size_t)(bm + ar) * D_ + k0 + sc8]);
    }
    *reinterpret_cast<int4*>(&Bs[srow][sc8]) =
        *reinterpret_cast<const int4*>(&Bt[(size_t)(bn + srow) * D_ + k0 + sc8]);
    __syncthreads();
    const bf16x8 av0 = *reinterpret_cast<const bf16x8*>(&As[r][g * 8]);
    const bf16x8 av1 = *reinterpret_cast<const bf16x8*>(&As[16 + r][g * 8]);
    const bf16x8 bv = *reinterpret_cast<const bf16x8*>(&Bs[w * 16 + r][g * 8]);
    acc0 = __builtin_amdgcn_mfma_f32_16x16x32_bf16(av0, bv, acc0, 0, 0, 0);
    acc1 = __builtin_amdgcn_mfma_f32_16x16x32_bf16(av1, bv, acc1, 0, 0, 0);
  }

  const int col = bn + w * 16 + r;
  const float bb = bias[col];
#pragma unroll
  for (int q = 0; q < 4; ++q) {
    const int row0 = bm + g * 4 + q;
    float v0 = acc0[q] + bb;
    v0 = v0 > 0.f ? v0 : 0.f;
    H[(size_t)row0 * D_ + col] = v0;
    float v1 = acc1[q] + bb;
    v1 = v1 > 0.f ? v1 : 0.f;
    H[(size_t)(row0 + 16) * D_ + col] = v1;
  }
}

// ---------------------------------------------------------------------------
// GEMM2: scores = H @ W2 + b2, written twice (tuple return).
// ---------------------------------------------------------------------------
#define ROWS 8

__global__ __launch_bounds__(128) void gemm2_kernel(
    const float* __restrict__ H, const float* __restrict__ W2,
    const float* __restrict__ b2, float* __restrict__ out) {
  __shared__ float hs[ROWS][D_];
  const int m0 = blockIdx.x * ROWS;
  const int t = threadIdx.x;

  const float4* src = reinterpret_cast<const float4*>(H + (size_t)m0 * D_);
  float4* dst = reinterpret_cast<float4*>(&hs[0][0]);
#pragma unroll
  for (int i = 0; i < 12; ++i) dst[t + i * 128] = src[t + i * 128];
  __syncthreads();

  if (t < C_) {
    float acc[ROWS] = {};
    for (int k = 0; k < D_; ++k) {
      const float wv = W2[(size_t)k * C_ + t];
#pragma unroll
      for (int r = 0; r < ROWS; ++r) acc[r] = fmaf(hs[r][k], wv, acc[r]);
    }
    const float bb = b2[t];
#pragma unroll
    for (int r = 0; r < ROWS; ++r) {
      const float v = acc[r] + bb;
      out[(size_t)(m0 + r) * C_ + t] = v;
      out[(size_t)(m0 + r) * C_ + t + (size_t)B_ * C_] = v;
    }
  }
}

// ---------------------------------------------------------------------------
extern "C" void kernel_launch(void* const* d_in, const int* in_sizes, int n_in,
                              void* d_out, int out_size, void* d_ws,
                              size_t ws_size, hipStream_t stream) {
  const int* ids = (const int*)d_in[0];
  const int* mask = (const int*)d_in[1];
  const float* table = (const float*)d_in[2];
  const float* W1 = (const float*)d_in[3];
  const float* b1 = (const float*)d_in[4];
  const float* W2 = (const float*)d_in[5];
  const float* b2 = (const float*)d_in[6];
  float* out = (float*)d_out;

  const size_t BOWB = (size_t)B_ * D_ * 2;          // 3.1 MB
  const size_t HB = (size_t)B_ * D_ * 4;            // 6.3 MB
  const size_t W1TB = (size_t)D_ * D_ * 2;          // 1.2 MB
  const size_t TBB = (size_t)V_ * D_ * 2;           // 46.9 MB

  char* p = (char*)d_ws;
  unsigned short* bowb = (unsigned short*)p;
  float* h = (float*)(p + BOWB);
  unsigned short* w1t = (unsigned short*)(p + BOWB + HB);
  unsigned short* tableb = (unsigned short*)(p + BOWB + HB + W1TB);
  const bool big = ws_size >= BOWB + HB + W1TB + TBB;

  conv_w1t<<<dim3(D_ / 32, D_ / 32), 256, 0, stream>>>(W1, w1t);
  if (big) {
    conv_table<<<2048, 256, 0, stream>>>(table, tableb, (V_ * D_) / 4);
    pool_bf16<<<B_, 192, 0, stream>>>(ids, mask, tableb, bowb);
  } else {
    pool_f32<<<B_, 192, 0, stream>>>(ids, mask, table, bowb);
  }
  gemm1_mfma<<<dim3(B_ / G1_BM, D_ / G1_BN), 256, 0, stream>>>(bowb, w1t, b1, h);
  gemm2_kernel<<<B_ / ROWS, 128, 0, stream>>>(h, W2, b2, out);
}

// Round 4
// 112.693 us; speedup vs baseline: 1.8983x; 1.3057x over previous
//
#include <hip/hip_runtime.h>

#define B_ 2048
#define S_ 256
#define V_ 30522
#define D_ 768
#define C_ 100
#define NPAD 112  // C_ padded to 7x16 for MFMA col tiles

// ---- bf16 helpers (RNE convert; inputs are finite, no NaN handling) -------
__device__ __forceinline__ unsigned short f2bf(float x) {
  unsigned u = __builtin_bit_cast(unsigned, x);
  u = (u + 0x7fffu + ((u >> 16) & 1u)) >> 16;
  return (unsigned short)u;
}
__device__ __forceinline__ float bf2f(unsigned short h) {
  return __builtin_bit_cast(float, ((unsigned)h) << 16);
}

typedef __attribute__((ext_vector_type(8))) short bf16x8;
typedef __attribute__((ext_vector_type(4))) float f32x4;

// ---------------------------------------------------------------------------
// Convert embedding table f32 -> bf16 (grid-stride, float4 in / ushort4 out)
// ---------------------------------------------------------------------------
__global__ __launch_bounds__(256) void conv_table(
    const float* __restrict__ src, unsigned short* __restrict__ dst, int n4) {
  int idx = blockIdx.x * blockDim.x + threadIdx.x;
  int stride = gridDim.x * blockDim.x;
  for (int i = idx; i < n4; i += stride) {
    float4 v = reinterpret_cast<const float4*>(src)[i];
    ushort4 o;
    o.x = f2bf(v.x); o.y = f2bf(v.y); o.z = f2bf(v.z); o.w = f2bf(v.w);
    reinterpret_cast<ushort4*>(dst)[i] = o;
  }
}

// ---------------------------------------------------------------------------
// Transpose + convert W1 [768][768] f32 -> W1T [n][k] bf16
// ---------------------------------------------------------------------------
__global__ __launch_bounds__(256) void conv_w1t(
    const float* __restrict__ w1, unsigned short* __restrict__ w1t) {
  __shared__ float tile[32][33];
  const int k0 = blockIdx.x * 32, n0 = blockIdx.y * 32;
  const int tx = threadIdx.x & 31, ty = threadIdx.x >> 5;  // ty 0..7
#pragma unroll
  for (int i = 0; i < 4; ++i)
    tile[ty + i * 8][tx] = w1[(size_t)(k0 + ty + i * 8) * D_ + n0 + tx];
  __syncthreads();
#pragma unroll
  for (int i = 0; i < 4; ++i) {
    const int n = ty + i * 8;
    w1t[(size_t)(n0 + n) * D_ + k0 + tx] = f2bf(tile[tx][n]);
  }
}

// ---------------------------------------------------------------------------
// Transpose + convert W2 [768][100] f32 -> W2T [112][768] bf16 (zero-padded)
// grid (24, 4): 32x32 k/n tiles (n range 0..127, write-guard n < 112)
// ---------------------------------------------------------------------------
__global__ __launch_bounds__(256) void conv_w2t(
    const float* __restrict__ w2, unsigned short* __restrict__ w2t) {
  __shared__ float tile[32][33];
  const int k0 = blockIdx.x * 32, n0 = blockIdx.y * 32;
  const int tx = threadIdx.x & 31, ty = threadIdx.x >> 5;
#pragma unroll
  for (int i = 0; i < 4; ++i) {
    const int k = k0 + ty + i * 8, n = n0 + tx;
    tile[ty + i * 8][tx] = (n < C_) ? w2[(size_t)k * C_ + n] : 0.f;
  }
  __syncthreads();
#pragma unroll
  for (int i = 0; i < 4; ++i) {
    const int n = n0 + ty + i * 8;
    if (n < NPAD)
      w2t[(size_t)n * D_ + k0 + tx] = f2bf(tile[tx][ty + i * 8]);
  }
}

// ---------------------------------------------------------------------------
// Pool (bf16 table): ballot-compact valid ids, then gather 16-deep.
// 192 threads; thread t owns 4 bf16 (8B) of D=768. Output bow in bf16.
// ---------------------------------------------------------------------------
__global__ __launch_bounds__(192) void pool_bf16(
    const int* __restrict__ ids, const int* __restrict__ mask,
    const unsigned short* __restrict__ tb, unsigned short* __restrict__ bowb) {
  __shared__ int vids[S_];
  __shared__ int s_cnt;
  const int b = blockIdx.x;
  const int t = threadIdx.x;
  const int base = b * S_;

  if (t < 64) {
    int total = 0;
#pragma unroll
    for (int r = 0; r < S_ / 64; ++r) {
      const int s = r * 64 + t;
      const int m = mask[base + s];
      const unsigned long long bal = __ballot(m != 0);
      const int pre = __popcll(bal & ((1ull << t) - 1ull));
      if (m) vids[total + pre] = ids[base + s];
      total += __popcll(bal);
    }
    if (t == 0) s_cnt = total;
  }
  __syncthreads();

  const int cnt = s_cnt;
  float a0 = 0.f, a1 = 0.f, a2 = 0.f, a3 = 0.f;

  int i = 0;
  for (; i + 16 <= cnt; i += 16) {
    ushort4 v[16];
#pragma unroll
    for (int j = 0; j < 16; ++j)
      v[j] = *(reinterpret_cast<const ushort4*>(tb + (size_t)vids[i + j] * D_) + t);
#pragma unroll
    for (int j = 0; j < 16; ++j) {
      a0 += bf2f(v[j].x); a1 += bf2f(v[j].y);
      a2 += bf2f(v[j].z); a3 += bf2f(v[j].w);
    }
  }
  for (; i < cnt; ++i) {
    const ushort4 v =
        *(reinterpret_cast<const ushort4*>(tb + (size_t)vids[i] * D_) + t);
    a0 += bf2f(v.x); a1 += bf2f(v.y); a2 += bf2f(v.z); a3 += bf2f(v.w);
  }

  const float inv = 1.0f / (float)cnt;
  ushort4 o;
  o.x = f2bf(a0 * inv); o.y = f2bf(a1 * inv);
  o.z = f2bf(a2 * inv); o.w = f2bf(a3 * inv);
  reinterpret_cast<ushort4*>(bowb + (size_t)b * D_)[t] = o;
}

// ---------------------------------------------------------------------------
// Pool fallback (f32 table, if ws too small for bf16 table). bf16 output.
// ---------------------------------------------------------------------------
__global__ __launch_bounds__(192) void pool_f32(
    const int* __restrict__ ids, const int* __restrict__ mask,
    const float* __restrict__ table, unsigned short* __restrict__ bowb) {
  __shared__ int vids[S_];
  __shared__ int s_cnt;
  const int b = blockIdx.x;
  const int t = threadIdx.x;
  const int base = b * S_;

  if (t < 64) {
    int total = 0;
#pragma unroll
    for (int r = 0; r < S_ / 64; ++r) {
      const int s = r * 64 + t;
      const int m = mask[base + s];
      const unsigned long long bal = __ballot(m != 0);
      const int pre = __popcll(bal & ((1ull << t) - 1ull));
      if (m) vids[total + pre] = ids[base + s];
      total += __popcll(bal);
    }
    if (t == 0) s_cnt = total;
  }
  __syncthreads();

  const int cnt = s_cnt;
  float4 acc = make_float4(0.f, 0.f, 0.f, 0.f);
  int i = 0;
  for (; i + 8 <= cnt; i += 8) {
    float4 v[8];
#pragma unroll
    for (int j = 0; j < 8; ++j)
      v[j] = reinterpret_cast<const float4*>(table + (size_t)vids[i + j] * D_)[t];
#pragma unroll
    for (int j = 0; j < 8; ++j) {
      acc.x += v[j].x; acc.y += v[j].y; acc.z += v[j].z; acc.w += v[j].w;
    }
  }
  for (; i < cnt; ++i) {
    const float4 v =
        reinterpret_cast<const float4*>(table + (size_t)vids[i] * D_)[t];
    acc.x += v.x; acc.y += v.y; acc.z += v.z; acc.w += v.w;
  }
  const float inv = 1.0f / (float)cnt;
  ushort4 o;
  o.x = f2bf(acc.x * inv); o.y = f2bf(acc.y * inv);
  o.z = f2bf(acc.z * inv); o.w = f2bf(acc.w * inv);
  reinterpret_cast<ushort4*>(bowb + (size_t)b * D_)[t] = o;
}

// ---------------------------------------------------------------------------
// GEMM1 (MFMA bf16): Hb = relu(bow @ W1 + b1), stored as bf16.
// A = bowb [2048][768] bf16 (k-contig), BT = w1t [768][768] bf16 (k-contig).
// Block 256 thr (4 waves), tile BM=32 x BN=64, BK=32.
// ---------------------------------------------------------------------------
#define G1_BM 32
#define G1_BN 64
#define G1_LDK 40  // 32 + 8 pad (ushorts) -> 80B row stride, 16B aligned

__global__ __launch_bounds__(256) void gemm1_mfma(
    const unsigned short* __restrict__ Ab, const unsigned short* __restrict__ Bt,
    const float* __restrict__ bias, unsigned short* __restrict__ Hb) {
  __shared__ unsigned short As[G1_BM][G1_LDK];
  __shared__ unsigned short Bs[G1_BN][G1_LDK];
  const int tid = threadIdx.x;
  const int bm = blockIdx.x * G1_BM;
  const int bn = blockIdx.y * G1_BN;
  const int w = tid >> 6;
  const int l = tid & 63;
  const int r = l & 15;
  const int g = l >> 4;

  f32x4 acc0 = {0.f, 0.f, 0.f, 0.f};
  f32x4 acc1 = {0.f, 0.f, 0.f, 0.f};

  const int srow = tid >> 2;        // 0..63
  const int sc8 = (tid & 3) * 8;    // 0,8,16,24 (bf16 elems)

  for (int k0 = 0; k0 < D_; k0 += 32) {
    __syncthreads();
    if (tid < 128) {
      const int ar = tid >> 2;      // 0..31
      *reinterpret_cast<int4*>(&As[ar][sc8]) =
          *reinterpret_cast<const int4*>(&Ab[(size_t)(bm + ar) * D_ + k0 + sc8]);
    }
    *reinterpret_cast<int4*>(&Bs[srow][sc8]) =
        *reinterpret_cast<const int4*>(&Bt[(size_t)(bn + srow) * D_ + k0 + sc8]);
    __syncthreads();
    const bf16x8 av0 = *reinterpret_cast<const bf16x8*>(&As[r][g * 8]);
    const bf16x8 av1 = *reinterpret_cast<const bf16x8*>(&As[16 + r][g * 8]);
    const bf16x8 bv = *reinterpret_cast<const bf16x8*>(&Bs[w * 16 + r][g * 8]);
    acc0 = __builtin_amdgcn_mfma_f32_16x16x32_bf16(av0, bv, acc0, 0, 0, 0);
    acc1 = __builtin_amdgcn_mfma_f32_16x16x32_bf16(av1, bv, acc1, 0, 0, 0);
  }

  const int col = bn + w * 16 + r;
  const float bb = bias[col];
#pragma unroll
  for (int q = 0; q < 4; ++q) {
    const int row0 = bm + g * 4 + q;
    float v0 = acc0[q] + bb;
    v0 = v0 > 0.f ? v0 : 0.f;
    Hb[(size_t)row0 * D_ + col] = f2bf(v0);
    float v1 = acc1[q] + bb;
    v1 = v1 > 0.f ? v1 : 0.f;
    Hb[(size_t)(row0 + 16) * D_ + col] = f2bf(v1);
  }
}

// ---------------------------------------------------------------------------
// GEMM2 (MFMA bf16): scores = Hb @ W2 + b2, written twice (tuple return).
// One wave per 16x16 output tile; K=768 fully unrolled (24 MFMA, operands
// loaded straight from global — hb (3 MB) and w2t (172 KB) are L2-resident).
// Grid (2048/16, 112/16) = (128, 7) = 896 waves.
// ---------------------------------------------------------------------------
__global__ __launch_bounds__(64) void gemm2_mfma(
    const unsigned short* __restrict__ Hb, const unsigned short* __restrict__ w2t,
    const float* __restrict__ b2, float* __restrict__ out) {
  const int bm = blockIdx.x * 16;
  const int bn = blockIdx.y * 16;
  const int l = threadIdx.x;
  const int r = l & 15;
  const int g = l >> 4;

  const unsigned short* ap = Hb + (size_t)(bm + r) * D_ + g * 8;
  const unsigned short* bp = w2t + (size_t)(bn + r) * D_ + g * 8;

  f32x4 acc = {0.f, 0.f, 0.f, 0.f};
#pragma unroll
  for (int k0 = 0; k0 < D_; k0 += 32) {
    const bf16x8 av = *reinterpret_cast<const bf16x8*>(ap + k0);
    const bf16x8 bv = *reinterpret_cast<const bf16x8*>(bp + k0);
    acc = __builtin_amdgcn_mfma_f32_16x16x32_bf16(av, bv, acc, 0, 0, 0);
  }

  const int col = bn + r;
  if (col < C_) {
    const float bb = b2[col];
#pragma unroll
    for (int q = 0; q < 4; ++q) {
      const int row = bm + g * 4 + q;
      const float v = acc[q] + bb;
      out[(size_t)row * C_ + col] = v;
      out[(size_t)row * C_ + col + (size_t)B_ * C_] = v;
    }
  }
}

// ---------------------------------------------------------------------------
extern "C" void kernel_launch(void* const* d_in, const int* in_sizes, int n_in,
                              void* d_out, int out_size, void* d_ws,
                              size_t ws_size, hipStream_t stream) {
  const int* ids = (const int*)d_in[0];
  const int* mask = (const int*)d_in[1];
  const float* table = (const float*)d_in[2];
  const float* W1 = (const float*)d_in[3];
  const float* b1 = (const float*)d_in[4];
  const float* W2 = (const float*)d_in[5];
  const float* b2 = (const float*)d_in[6];
  float* out = (float*)d_out;

  const size_t BOWB = (size_t)B_ * D_ * 2;          // 3.1 MB
  const size_t HBB  = (size_t)B_ * D_ * 2;          // 3.1 MB
  const size_t W1TB = (size_t)D_ * D_ * 2;          // 1.2 MB
  const size_t W2TB = (size_t)NPAD * D_ * 2;        // 172 KB
  const size_t TBB  = (size_t)V_ * D_ * 2;          // 46.9 MB

  char* p = (char*)d_ws;
  unsigned short* bowb   = (unsigned short*)p;
  unsigned short* hb     = (unsigned short*)(p + BOWB);
  unsigned short* w1t    = (unsigned short*)(p + BOWB + HBB);
  unsigned short* w2t    = (unsigned short*)(p + BOWB + HBB + W1TB);
  unsigned short* tableb = (unsigned short*)(p + BOWB + HBB + W1TB + W2TB);
  const bool big = ws_size >= BOWB + HBB + W1TB + W2TB + TBB;

  conv_w1t<<<dim3(D_ / 32, D_ / 32), 256, 0, stream>>>(W1, w1t);
  conv_w2t<<<dim3(D_ / 32, 4), 256, 0, stream>>>(W2, w2t);
  if (big) {
    conv_table<<<2048, 256, 0, stream>>>(table, tableb, (V_ * D_) / 4);
    pool_bf16<<<B_, 192, 0, stream>>>(ids, mask, tableb, bowb);
  } else {
    pool_f32<<<B_, 192, 0, stream>>>(ids, mask, table, bowb);
  }
  gemm1_mfma<<<dim3(B_ / G1_BM, D_ / G1_BN), 256, 0, stream>>>(bowb, w1t, b1, hb);
  gemm2_mfma<<<dim3(B_ / 16, NPAD / 16), 64, 0, stream>>>(hb, w2t, b2, out);
}

// Round 5
// 111.681 us; speedup vs baseline: 1.9155x; 1.0091x over previous
//
#include <hip/hip_runtime.h>

#define B_ 2048
#define S_ 256
#define V_ 30522
#define D_ 768
#define C_ 100
#define NPAD 112  // C_ padded to 7x16 for MFMA col tiles

// ---- bf16 helpers (RNE convert; inputs are finite, no NaN handling) -------
__device__ __forceinline__ unsigned short f2bf(float x) {
  unsigned u = __builtin_bit_cast(unsigned, x);
  u = (u + 0x7fffu + ((u >> 16) & 1u)) >> 16;
  return (unsigned short)u;
}
__device__ __forceinline__ float bf2f(unsigned short h) {
  return __builtin_bit_cast(float, ((unsigned)h) << 16);
}
__device__ __forceinline__ float bf_lo(unsigned u) {  // low 16 bits as bf16
  return __builtin_bit_cast(float, u << 16);
}
__device__ __forceinline__ float bf_hi(unsigned u) {  // high 16 bits as bf16
  return __builtin_bit_cast(float, u & 0xffff0000u);
}

typedef __attribute__((ext_vector_type(8))) short bf16x8;
typedef __attribute__((ext_vector_type(4))) float f32x4;

// ---------------------------------------------------------------------------
// Convert embedding table f32 -> bf16 (grid-stride, float4 in / ushort4 out)
// ---------------------------------------------------------------------------
__global__ __launch_bounds__(256) void conv_table(
    const float* __restrict__ src, unsigned short* __restrict__ dst, int n4) {
  int idx = blockIdx.x * blockDim.x + threadIdx.x;
  int stride = gridDim.x * blockDim.x;
  for (int i = idx; i < n4; i += stride) {
    float4 v = reinterpret_cast<const float4*>(src)[i];
    ushort4 o;
    o.x = f2bf(v.x); o.y = f2bf(v.y); o.z = f2bf(v.z); o.w = f2bf(v.w);
    reinterpret_cast<ushort4*>(dst)[i] = o;
  }
}

// ---------------------------------------------------------------------------
// Transpose + convert W1 [768][768] f32 -> W1T [n][k] bf16
// ---------------------------------------------------------------------------
__global__ __launch_bounds__(256) void conv_w1t(
    const float* __restrict__ w1, unsigned short* __restrict__ w1t) {
  __shared__ float tile[32][33];
  const int k0 = blockIdx.x * 32, n0 = blockIdx.y * 32;
  const int tx = threadIdx.x & 31, ty = threadIdx.x >> 5;  // ty 0..7
#pragma unroll
  for (int i = 0; i < 4; ++i)
    tile[ty + i * 8][tx] = w1[(size_t)(k0 + ty + i * 8) * D_ + n0 + tx];
  __syncthreads();
#pragma unroll
  for (int i = 0; i < 4; ++i) {
    const int n = ty + i * 8;
    w1t[(size_t)(n0 + n) * D_ + k0 + tx] = f2bf(tile[tx][n]);
  }
}

// ---------------------------------------------------------------------------
// Transpose + convert W2 [768][100] f32 -> W2T [112][768] bf16 (zero-padded)
// ---------------------------------------------------------------------------
__global__ __launch_bounds__(256) void conv_w2t(
    const float* __restrict__ w2, unsigned short* __restrict__ w2t) {
  __shared__ float tile[32][33];
  const int k0 = blockIdx.x * 32, n0 = blockIdx.y * 32;
  const int tx = threadIdx.x & 31, ty = threadIdx.x >> 5;
#pragma unroll
  for (int i = 0; i < 4; ++i) {
    const int k = k0 + ty + i * 8, n = n0 + tx;
    tile[ty + i * 8][tx] = (n < C_) ? w2[(size_t)k * C_ + n] : 0.f;
  }
  __syncthreads();
#pragma unroll
  for (int i = 0; i < 4; ++i) {
    const int n = n0 + ty + i * 8;
    if (n < NPAD)
      w2t[(size_t)n * D_ + k0 + tx] = f2bf(tile[tx][ty + i * 8]);
  }
}

// ---------------------------------------------------------------------------
// Pool v2 (bf16 table): 2 samples per 192-thread block; 96 lanes per sample,
// each lane owns 8 bf16 (16 B) of D=768. Ballot-compact ids (waves 0,1),
// then gather 8-deep batches of int4 loads (~32 VGPRs of data in flight).
// ---------------------------------------------------------------------------
__global__ __launch_bounds__(192) void pool_bf16(
    const int* __restrict__ ids, const int* __restrict__ mask,
    const unsigned short* __restrict__ tb, unsigned short* __restrict__ bowb) {
  __shared__ int vids[2][S_];
  __shared__ int s_cnt[2];
  const int t = threadIdx.x;
  const int b0 = blockIdx.x * 2;
  const int w = t >> 6;

  if (w < 2) {  // wave w compacts sample b0+w
    const int lane = t & 63;
    const int base = (b0 + w) * S_;
    int total = 0;
#pragma unroll
    for (int r = 0; r < S_ / 64; ++r) {
      const int s = r * 64 + lane;
      const int m = mask[base + s];
      const unsigned long long bal = __ballot(m != 0);
      const int pre = __popcll(bal & ((1ull << lane) - 1ull));
      if (m) vids[w][total + pre] = ids[base + s];
      total += __popcll(bal);
    }
    if (lane == 0) s_cnt[w] = total;
  }
  __syncthreads();

  const int sel = t / 96;   // which sample (0/1)
  const int c8 = t % 96;    // 16B chunk of the row
  const int cnt = s_cnt[sel];
  const int* vp = vids[sel];
  const unsigned short* tbc = tb + (size_t)c8 * 8;

  float a[8] = {};
  int i = 0;
  for (; i + 8 <= cnt; i += 8) {
    int4 v[8];
#pragma unroll
    for (int j = 0; j < 8; ++j)
      v[j] = *reinterpret_cast<const int4*>(tbc + (size_t)vp[i + j] * D_);
#pragma unroll
    for (int j = 0; j < 8; ++j) {
      const unsigned* u = reinterpret_cast<const unsigned*>(&v[j]);
#pragma unroll
      for (int q = 0; q < 4; ++q) {
        a[2 * q]     += bf_lo(u[q]);
        a[2 * q + 1] += bf_hi(u[q]);
      }
    }
  }
  for (; i < cnt; ++i) {
    const int4 v = *reinterpret_cast<const int4*>(tbc + (size_t)vp[i] * D_);
    const unsigned* u = reinterpret_cast<const unsigned*>(&v);
#pragma unroll
    for (int q = 0; q < 4; ++q) {
      a[2 * q]     += bf_lo(u[q]);
      a[2 * q + 1] += bf_hi(u[q]);
    }
  }

  const float inv = 1.0f / (float)cnt;
  ushort4 o[2];
#pragma unroll
  for (int q = 0; q < 4; ++q) {
    reinterpret_cast<unsigned short*>(o)[2 * q]     = f2bf(a[2 * q] * inv);
    reinterpret_cast<unsigned short*>(o)[2 * q + 1] = f2bf(a[2 * q + 1] * inv);
  }
  *reinterpret_cast<int4*>(bowb + (size_t)(b0 + sel) * D_ + (size_t)c8 * 8) =
      *reinterpret_cast<const int4*>(o);
}

// ---------------------------------------------------------------------------
// Pool fallback (f32 table, if ws too small for bf16 table). bf16 output.
// ---------------------------------------------------------------------------
__global__ __launch_bounds__(192) void pool_f32(
    const int* __restrict__ ids, const int* __restrict__ mask,
    const float* __restrict__ table, unsigned short* __restrict__ bowb) {
  __shared__ int vids[S_];
  __shared__ int s_cnt;
  const int b = blockIdx.x;
  const int t = threadIdx.x;
  const int base = b * S_;

  if (t < 64) {
    int total = 0;
#pragma unroll
    for (int r = 0; r < S_ / 64; ++r) {
      const int s = r * 64 + t;
      const int m = mask[base + s];
      const unsigned long long bal = __ballot(m != 0);
      const int pre = __popcll(bal & ((1ull << t) - 1ull));
      if (m) vids[total + pre] = ids[base + s];
      total += __popcll(bal);
    }
    if (t == 0) s_cnt = total;
  }
  __syncthreads();

  const int cnt = s_cnt;
  float4 acc = make_float4(0.f, 0.f, 0.f, 0.f);
  int i = 0;
  for (; i + 8 <= cnt; i += 8) {
    float4 v[8];
#pragma unroll
    for (int j = 0; j < 8; ++j)
      v[j] = reinterpret_cast<const float4*>(table + (size_t)vids[i + j] * D_)[t];
#pragma unroll
    for (int j = 0; j < 8; ++j) {
      acc.x += v[j].x; acc.y += v[j].y; acc.z += v[j].z; acc.w += v[j].w;
    }
  }
  for (; i < cnt; ++i) {
    const float4 v =
        reinterpret_cast<const float4*>(table + (size_t)vids[i] * D_)[t];
    acc.x += v.x; acc.y += v.y; acc.z += v.z; acc.w += v.w;
  }
  const float inv = 1.0f / (float)cnt;
  ushort4 o;
  o.x = f2bf(acc.x * inv); o.y = f2bf(acc.y * inv);
  o.z = f2bf(acc.z * inv); o.w = f2bf(acc.w * inv);
  reinterpret_cast<ushort4*>(bowb + (size_t)b * D_)[t] = o;
}

// ---------------------------------------------------------------------------
// GEMM1 (MFMA bf16): Hb = relu(bow @ W1 + b1), stored as bf16.
// ---------------------------------------------------------------------------
#define G1_BM 32
#define G1_BN 64
#define G1_LDK 40  // 32 + 8 pad (ushorts) -> 80B row stride, 16B aligned

__global__ __launch_bounds__(256) void gemm1_mfma(
    const unsigned short* __restrict__ Ab, const unsigned short* __restrict__ Bt,
    const float* __restrict__ bias, unsigned short* __restrict__ Hb) {
  __shared__ unsigned short As[G1_BM][G1_LDK];
  __shared__ unsigned short Bs[G1_BN][G1_LDK];
  const int tid = threadIdx.x;
  const int bm = blockIdx.x * G1_BM;
  const int bn = blockIdx.y * G1_BN;
  const int w = tid >> 6;
  const int l = tid & 63;
  const int r = l & 15;
  const int g = l >> 4;

  f32x4 acc0 = {0.f, 0.f, 0.f, 0.f};
  f32x4 acc1 = {0.f, 0.f, 0.f, 0.f};

  const int srow = tid >> 2;        // 0..63
  const int sc8 = (tid & 3) * 8;    // 0,8,16,24 (bf16 elems)

  for (int k0 = 0; k0 < D_; k0 += 32) {
    __syncthreads();
    if (tid < 128) {
      const int ar = tid >> 2;      // 0..31
      *reinterpret_cast<int4*>(&As[ar][sc8]) =
          *reinterpret_cast<const int4*>(&Ab[(size_t)(bm + ar) * D_ + k0 + sc8]);
    }
    *reinterpret_cast<int4*>(&Bs[srow][sc8]) =
        *reinterpret_cast<const int4*>(&Bt[(size_t)(bn + srow) * D_ + k0 + sc8]);
    __syncthreads();
    const bf16x8 av0 = *reinterpret_cast<const bf16x8*>(&As[r][g * 8]);
    const bf16x8 av1 = *reinterpret_cast<const bf16x8*>(&As[16 + r][g * 8]);
    const bf16x8 bv = *reinterpret_cast<const bf16x8*>(&Bs[w * 16 + r][g * 8]);
    acc0 = __builtin_amdgcn_mfma_f32_16x16x32_bf16(av0, bv, acc0, 0, 0, 0);
    acc1 = __builtin_amdgcn_mfma_f32_16x16x32_bf16(av1, bv, acc1, 0, 0, 0);
  }

  const int col = bn + w * 16 + r;
  const float bb = bias[col];
#pragma unroll
  for (int q = 0; q < 4; ++q) {
    const int row0 = bm + g * 4 + q;
    float v0 = acc0[q] + bb;
    v0 = v0 > 0.f ? v0 : 0.f;
    Hb[(size_t)row0 * D_ + col] = f2bf(v0);
    float v1 = acc1[q] + bb;
    v1 = v1 > 0.f ? v1 : 0.f;
    Hb[(size_t)(row0 + 16) * D_ + col] = f2bf(v1);
  }
}

// ---------------------------------------------------------------------------
// GEMM2 (MFMA bf16): scores = Hb @ W2 + b2, written twice (tuple return).
// ---------------------------------------------------------------------------
__global__ __launch_bounds__(64) void gemm2_mfma(
    const unsigned short* __restrict__ Hb, const unsigned short* __restrict__ w2t,
    const float* __restrict__ b2, float* __restrict__ out) {
  const int bm = blockIdx.x * 16;
  const int bn = blockIdx.y * 16;
  const int l = threadIdx.x;
  const int r = l & 15;
  const int g = l >> 4;

  const unsigned short* ap = Hb + (size_t)(bm + r) * D_ + g * 8;
  const unsigned short* bp = w2t + (size_t)(bn + r) * D_ + g * 8;

  f32x4 acc = {0.f, 0.f, 0.f, 0.f};
#pragma unroll
  for (int k0 = 0; k0 < D_; k0 += 32) {
    const bf16x8 av = *reinterpret_cast<const bf16x8*>(ap + k0);
    const bf16x8 bv = *reinterpret_cast<const bf16x8*>(bp + k0);
    acc = __builtin_amdgcn_mfma_f32_16x16x32_bf16(av, bv, acc, 0, 0, 0);
  }

  const int col = bn + r;
  if (col < C_) {
    const float bb = b2[col];
#pragma unroll
    for (int q = 0; q < 4; ++q) {
      const int row = bm + g * 4 + q;
      const float v = acc[q] + bb;
      out[(size_t)row * C_ + col] = v;
      out[(size_t)row * C_ + col + (size_t)B_ * C_] = v;
    }
  }
}

// ---------------------------------------------------------------------------
extern "C" void kernel_launch(void* const* d_in, const int* in_sizes, int n_in,
                              void* d_out, int out_size, void* d_ws,
                              size_t ws_size, hipStream_t stream) {
  const int* ids = (const int*)d_in[0];
  const int* mask = (const int*)d_in[1];
  const float* table = (const float*)d_in[2];
  const float* W1 = (const float*)d_in[3];
  const float* b1 = (const float*)d_in[4];
  const float* W2 = (const float*)d_in[5];
  const float* b2 = (const float*)d_in[6];
  float* out = (float*)d_out;

  const size_t BOWB = (size_t)B_ * D_ * 2;          // 3.1 MB
  const size_t HBB  = (size_t)B_ * D_ * 2;          // 3.1 MB
  const size_t W1TB = (size_t)D_ * D_ * 2;          // 1.2 MB
  const size_t W2TB = (size_t)NPAD * D_ * 2;        // 172 KB
  const size_t TBB  = (size_t)V_ * D_ * 2;          // 46.9 MB

  char* p = (char*)d_ws;
  unsigned short* bowb   = (unsigned short*)p;
  unsigned short* hb     = (unsigned short*)(p + BOWB);
  unsigned short* w1t    = (unsigned short*)(p + BOWB + HBB);
  unsigned short* w2t    = (unsigned short*)(p + BOWB + HBB + W1TB);
  unsigned short* tableb = (unsigned short*)(p + BOWB + HBB + W1TB + W2TB);
  const bool big = ws_size >= BOWB + HBB + W1TB + W2TB + TBB;

  conv_w1t<<<dim3(D_ / 32, D_ / 32), 256, 0, stream>>>(W1, w1t);
  conv_w2t<<<dim3(D_ / 32, 4), 256, 0, stream>>>(W2, w2t);
  if (big) {
    conv_table<<<2048, 256, 0, stream>>>(table, tableb, (V_ * D_) / 4);
    pool_bf16<<<B_ / 2, 192, 0, stream>>>(ids, mask, tableb, bowb);
  } else {
    pool_f32<<<B_, 192, 0, stream>>>(ids, mask, table, bowb);
  }
  gemm1_mfma<<<dim3(B_ / G1_BM, D_ / G1_BN), 256, 0, stream>>>(bowb, w1t, b1, hb);
  gemm2_mfma<<<dim3(B_ / 16, NPAD / 16), 64, 0, stream>>>(hb, w2t, b2, out);
}